// Round 1
// baseline (772.586 us; speedup 1.0000x reference)
//
#include <hip/hip_runtime.h>

#define GI  1220          // g_i feature dim
#define KP  1280          // K padded to 40 * 32
#define BK  128           // K-chunk staged in LDS
#define NCH (KP / BK)     // 10 chunks
#define NP  192           // hidden dim padded 150 -> 192 (12 * 16)
#define ABW 320           // AB row: A[0:160) | B[160:320), cols >=150 zero

typedef __bf16        bf16x8 __attribute__((ext_vector_type(8)));
typedef float         f32x4  __attribute__((ext_vector_type(4)));
typedef unsigned int  u32x4  __attribute__((ext_vector_type(4)));
typedef unsigned int  u32x2  __attribute__((ext_vector_type(2)));

__device__ __forceinline__ unsigned short f2bf(float f) {
  __bf16 h = (__bf16)f;
  return __builtin_bit_cast(unsigned short, h);
}
__device__ __forceinline__ float bf2f(unsigned short u) {
  return (float)__builtin_bit_cast(__bf16, u);
}
__device__ __forceinline__ unsigned int pk2(float a, float b) {
  return (unsigned int)f2bf(a) | ((unsigned int)f2bf(b) << 16);
}

// ---------------------------------------------------------------------------
// prep: build bf16 transposed weight layouts + fp32 proj tables in ws.
//  W1ab_t [320][KP]  n-major, k-contig:  n<150 -> W1a col n ; 160<=n<310 -> W1b col n-160
//  W1c_t  [192][KP]  n-major, k-contig:  W1 rows 2440..3659
//  W2_t   [192][192] n-major, k-contig
//  projs  [20][192]  fp32: rows 0..8 dist (+b1 folded), 9..16 genre, 17..19 speaker
// ---------------------------------------------------------------------------
__global__ void prep_kernel(const float* __restrict__ W1, const float* __restrict__ W2,
                            const float* __restrict__ b1,
                            const float* __restrict__ de, const float* __restrict__ ge,
                            const float* __restrict__ se,
                            unsigned short* __restrict__ W1ab_t,
                            unsigned short* __restrict__ W1c_t,
                            unsigned short* __restrict__ W2_t,
                            float* __restrict__ projs) {
  int idx = blockIdx.x * 256 + threadIdx.x;
  const int R1 = ABW * KP, R2 = NP * KP, R3 = NP * NP, R4 = 20 * NP;
  if (idx < R1) {
    int n = idx / KP, k = idx % KP;
    float v = 0.f;
    if (k < GI) {
      if (n < 150)                 v = W1[k * 150 + n];
      else if (n >= 160 && n < 310) v = W1[(GI + k) * 150 + (n - 160)];
    }
    W1ab_t[idx] = f2bf(v);
    return;
  }
  idx -= R1;
  if (idx < R2) {
    int n = idx / KP, k = idx % KP;
    float v = (k < GI && n < 150) ? W1[(2 * GI + k) * 150 + n] : 0.f;
    W1c_t[idx] = f2bf(v);
    return;
  }
  idx -= R2;
  if (idx < R3) {
    int n = idx / NP, k = idx % NP;
    float v = (n < 150 && k < 150) ? W2[k * 150 + n] : 0.f;
    W2_t[idx] = f2bf(v);
    return;
  }
  idx -= R3;
  if (idx < R4) {
    int r = idx / NP, n = idx % NP;
    float v = 0.f;
    if (n < 150) {
      if (r < 9) {
        v = b1[n];
        for (int t = 0; t < 20; ++t) v += de[r * 20 + t] * W1[(3660 + t) * 150 + n];
      } else if (r < 17) {
        int q = r - 9;
        for (int t = 0; t < 20; ++t) v += ge[q * 20 + t] * W1[(3680 + t) * 150 + n];
      } else {
        int q = r - 17;
        for (int t = 0; t < 20; ++t) v += se[q * 20 + t] * W1[(3700 + t) * 150 + n];
      }
    }
    projs[idx] = v;
  }
}

// ---------------------------------------------------------------------------
// ab_kernel:  AB[m][0:160) = (G @ W1a)[m],  AB[m][160:320) = (G @ W1b)[m], bf16.
// Block: 256 thr (4 waves), M-tile 64, N=320 (wave w -> ntiles w*5..w*5+4, all 4 msubs).
// ---------------------------------------------------------------------------
__global__ __launch_bounds__(256, 3)
void ab_kernel(const float* __restrict__ g, const unsigned short* __restrict__ W1ab_t,
               unsigned short* __restrict__ AB, int N) {
  __shared__ __attribute__((aligned(16))) unsigned short sX[64 * 136];
  const int t = threadIdx.x;
  const int m0 = blockIdx.x * 64;
  const int w = t >> 6, lane = t & 63, quad = lane >> 4, lm = lane & 15;

  f32x4 acc[4][5];
#pragma unroll
  for (int a = 0; a < 4; ++a)
#pragma unroll
    for (int b = 0; b < 5; ++b) { acc[a][b].x = 0.f; acc[a][b].y = 0.f; acc[a][b].z = 0.f; acc[a][b].w = 0.f; }

  const int r = t >> 2, s = t & 3;
  int row = m0 + r; if (row >= N) row = N - 1;
  const float* gr = g + (long)row * GI;

  for (int c = 0; c < NCH; ++c) {
    __syncthreads();
#pragma unroll
    for (int i = 0; i < 8; ++i) {
      int k = c * BK + i * 16 + s * 4;
      u32x2 pk; pk.x = 0u; pk.y = 0u;
      if (k < GI) {
        f32x4 x = *(const f32x4*)(gr + k);
        pk.x = pk2(x.x, x.y);
        pk.y = pk2(x.z, x.w);
      }
      *(u32x2*)&sX[r * 136 + i * 16 + s * 4] = pk;
    }
    __syncthreads();
#pragma unroll
    for (int kk = 0; kk < 4; ++kk) {
      bf16x8 af[4];
#pragma unroll
      for (int mi = 0; mi < 4; ++mi)
        af[mi] = __builtin_bit_cast(bf16x8, *(const u32x4*)&sX[(mi * 16 + lm) * 136 + kk * 32 + quad * 8]);
#pragma unroll
      for (int tl = 0; tl < 5; ++tl) {
        int n = (w * 5 + tl) * 16 + lm;
        bf16x8 bfr = __builtin_bit_cast(bf16x8, *(const u32x4*)(W1ab_t + n * KP + c * BK + kk * 32 + quad * 8));
#pragma unroll
        for (int mi = 0; mi < 4; ++mi)
          acc[mi][tl] = __builtin_amdgcn_mfma_f32_16x16x32_bf16(af[mi], bfr, acc[mi][tl], 0, 0, 0);
      }
    }
  }
#pragma unroll
  for (int mi = 0; mi < 4; ++mi)
#pragma unroll
    for (int reg = 0; reg < 4; ++reg) {
      int m = m0 + mi * 16 + quad * 4 + reg;
      if (m < N) {
#pragma unroll
        for (int tl = 0; tl < 5; ++tl) {
          int n = (w * 5 + tl) * 16 + lm;
          AB[(long)m * ABW + n] = f2bf(acc[mi][tl][reg]);
        }
      }
    }
}

// ---------------------------------------------------------------------------
// pair_kernel: fused per 64 pairs. bilinear MFMA + bias(A,B,proj) + relu
//              -> layer2 MFMA + relu -> layer3 dot -> sij.
// ---------------------------------------------------------------------------
__global__ __launch_bounds__(256, 3)
void pair_kernel(const float* __restrict__ g, const float* __restrict__ msc,
                 const unsigned short* __restrict__ AB,
                 const unsigned short* __restrict__ W1c_t,
                 const unsigned short* __restrict__ W2_t,
                 const float* __restrict__ projs,
                 const float* __restrict__ b2, const float* __restrict__ W3,
                 const float* __restrict__ b3,
                 const int* __restrict__ mid, const int* __restrict__ aid,
                 const int* __restrict__ did, const int* __restrict__ gid,
                 const int* __restrict__ sid,
                 float* __restrict__ out, int N, int P) {
  __shared__ __attribute__((aligned(16))) unsigned short sXh1[64 * 200];  // X stage (stride 136) / h1 (stride 200)
  __shared__ __attribute__((aligned(16))) unsigned short sBias[64 * NP];  // bias (then h2)
  __shared__ int sM[64], sA[64], sD[64], sG[64], sS[64];
  __shared__ float sScore[64];

  const int t = threadIdx.x;
  const int p0 = blockIdx.x * 64;
  const int w = t >> 6, lane = t & 63, quad = lane >> 4, lm = lane & 15;

  if (t < 64) {
    int p = p0 + t;
    int m_ = 0, a_ = 0, d_ = 0, g_ = 0, s_ = 0;
    float sc = 0.f;
    if (p < P) {
      m_ = mid[p]; a_ = aid[p]; d_ = did[p]; g_ = gid[p]; s_ = sid[p];
      sc = msc[m_] + msc[a_];
    }
    sM[t] = m_; sA[t] = a_; sD[t] = d_; sG[t] = g_; sS[t] = s_;
    sScore[t] = sc;
  }
  __syncthreads();

  const int r = t >> 2, s = t & 3;
  const float* gm = g + (long)sM[r] * GI;
  const float* ga = g + (long)sA[r] * GI;

  // ---- bias tile: bias[m][n] = A[mid][n] + B[aid][n] + dist+genre+speaker proj (b1 folded)
  {
    const unsigned short* Ar = AB + (long)sM[r] * ABW;
    const unsigned short* Br = AB + (long)sA[r] * ABW + 160;
    const float* dp = projs + sD[r] * NP;
    const float* gp = projs + (9 + sG[r]) * NP;
    const float* sp = projs + (17 + sS[r]) * NP;
#pragma unroll
    for (int j = 0; j < 6; ++j) {
      int n = s * 48 + j * 8;
      f32x4 p0v = *(const f32x4*)(dp + n) + *(const f32x4*)(gp + n) + *(const f32x4*)(sp + n);
      f32x4 p1v = *(const f32x4*)(dp + n + 4) + *(const f32x4*)(gp + n + 4) + *(const f32x4*)(sp + n + 4);
      if (n < 160) {
        u32x4 a8 = *(const u32x4*)(Ar + n);
        u32x4 b8 = *(const u32x4*)(Br + n);
        p0v.x += bf2f(a8.x & 0xffff) + bf2f(b8.x & 0xffff);
        p0v.y += bf2f(a8.x >> 16)    + bf2f(b8.x >> 16);
        p0v.z += bf2f(a8.y & 0xffff) + bf2f(b8.y & 0xffff);
        p0v.w += bf2f(a8.y >> 16)    + bf2f(b8.y >> 16);
        p1v.x += bf2f(a8.z & 0xffff) + bf2f(b8.z & 0xffff);
        p1v.y += bf2f(a8.z >> 16)    + bf2f(b8.z >> 16);
        p1v.z += bf2f(a8.w & 0xffff) + bf2f(b8.w & 0xffff);
        p1v.w += bf2f(a8.w >> 16)    + bf2f(b8.w >> 16);
      }
      u32x4 o;
      o.x = pk2(p0v.x, p0v.y); o.y = pk2(p0v.z, p0v.w);
      o.z = pk2(p1v.x, p1v.y); o.w = pk2(p1v.z, p1v.w);
      *(u32x4*)&sBias[r * NP + n] = o;
    }
  }

  // ---- layer 1 bilinear: acc[msub][tl] over K = 1280 (zero-padded past 1220)
  f32x4 acc[4][3];
#pragma unroll
  for (int a = 0; a < 4; ++a)
#pragma unroll
    for (int b = 0; b < 3; ++b) { acc[a][b].x = 0.f; acc[a][b].y = 0.f; acc[a][b].z = 0.f; acc[a][b].w = 0.f; }

  for (int c = 0; c < NCH; ++c) {
    __syncthreads();
#pragma unroll
    for (int i = 0; i < 8; ++i) {
      int k = c * BK + i * 16 + s * 4;
      u32x2 pk; pk.x = 0u; pk.y = 0u;
      if (k < GI) {
        f32x4 x = *(const f32x4*)(gm + k);
        f32x4 y = *(const f32x4*)(ga + k);
        pk.x = pk2(x.x * y.x, x.y * y.y);
        pk.y = pk2(x.z * y.z, x.w * y.w);
      }
      *(u32x2*)&sXh1[r * 136 + i * 16 + s * 4] = pk;
    }
    __syncthreads();
#pragma unroll
    for (int kk = 0; kk < 4; ++kk) {
      bf16x8 af[4];
#pragma unroll
      for (int mi = 0; mi < 4; ++mi)
        af[mi] = __builtin_bit_cast(bf16x8, *(const u32x4*)&sXh1[(mi * 16 + lm) * 136 + kk * 32 + quad * 8]);
#pragma unroll
      for (int tl = 0; tl < 3; ++tl) {
        int n = (w * 3 + tl) * 16 + lm;
        bf16x8 bfr = __builtin_bit_cast(bf16x8, *(const u32x4*)(W1c_t + n * KP + c * BK + kk * 32 + quad * 8));
#pragma unroll
        for (int mi = 0; mi < 4; ++mi)
          acc[mi][tl] = __builtin_amdgcn_mfma_f32_16x16x32_bf16(af[mi], bfr, acc[mi][tl], 0, 0, 0);
      }
    }
  }

  // ---- epilogue 1: + bias, relu, h1 -> LDS (A-layout, stride 200)
  __syncthreads();
#pragma unroll
  for (int mi = 0; mi < 4; ++mi)
#pragma unroll
    for (int tl = 0; tl < 3; ++tl) {
      int n = (w * 3 + tl) * 16 + lm;
#pragma unroll
      for (int reg = 0; reg < 4; ++reg) {
        int m = mi * 16 + quad * 4 + reg;
        float v = acc[mi][tl][reg] + bf2f(sBias[m * NP + n]);
        v = fmaxf(v, 0.f);
        sXh1[m * 200 + n] = f2bf(v);
      }
    }
  __syncthreads();

  // ---- layer 2: h1[64][192] @ W2_t
  f32x4 acc2[4][3];
#pragma unroll
  for (int a = 0; a < 4; ++a)
#pragma unroll
    for (int b = 0; b < 3; ++b) { acc2[a][b].x = 0.f; acc2[a][b].y = 0.f; acc2[a][b].z = 0.f; acc2[a][b].w = 0.f; }
#pragma unroll
  for (int kk = 0; kk < 6; ++kk) {
    bf16x8 af[4];
#pragma unroll
    for (int mi = 0; mi < 4; ++mi)
      af[mi] = __builtin_bit_cast(bf16x8, *(const u32x4*)&sXh1[(mi * 16 + lm) * 200 + kk * 32 + quad * 8]);
#pragma unroll
    for (int tl = 0; tl < 3; ++tl) {
      int n = (w * 3 + tl) * 16 + lm;
      bf16x8 bfr = __builtin_bit_cast(bf16x8, *(const u32x4*)(W2_t + n * NP + kk * 32 + quad * 8));
#pragma unroll
      for (int mi = 0; mi < 4; ++mi)
        acc2[mi][tl] = __builtin_amdgcn_mfma_f32_16x16x32_bf16(af[mi], bfr, acc2[mi][tl], 0, 0, 0);
    }
  }

  // ---- epilogue 2: + b2, relu, h2 -> sBias region (stride NP)
#pragma unroll
  for (int mi = 0; mi < 4; ++mi)
#pragma unroll
    for (int tl = 0; tl < 3; ++tl) {
      int n = (w * 3 + tl) * 16 + lm;
      float bb = (n < 150) ? b2[n] : 0.f;
#pragma unroll
      for (int reg = 0; reg < 4; ++reg) {
        int m = mi * 16 + quad * 4 + reg;
        float v = acc2[mi][tl][reg] + bb;
        v = fmaxf(v, 0.f);
        sBias[m * NP + n] = f2bf(v);
      }
    }
  __syncthreads();

  // ---- layer 3: pairwise = h2 . W3 ; sij = ms_i + ms_j + pairwise + b3
  {
    float sum = 0.f;
#pragma unroll
    for (int j = 0; j < 48; ++j) {
      int n = s * 48 + j;
      if (n < 150) sum += bf2f(sBias[r * NP + n]) * W3[n];
    }
    sum += __shfl_xor(sum, 1);
    sum += __shfl_xor(sum, 2);
    if (s == 0) {
      int p = p0 + r;
      if (p < P) out[p] = sScore[r] + sum + b3[0];
    }
  }
}

extern "C" void kernel_launch(void* const* d_in, const int* in_sizes, int n_in,
                              void* d_out, int out_size, void* d_ws, size_t ws_size,
                              hipStream_t stream) {
  (void)n_in; (void)out_size; (void)ws_size;
  const float* g   = (const float*)d_in[0];
  const float* msc = (const float*)d_in[1];
  const float* de  = (const float*)d_in[2];
  const float* ge  = (const float*)d_in[3];
  const float* se  = (const float*)d_in[4];
  const float* W1  = (const float*)d_in[5];
  const float* b1  = (const float*)d_in[6];
  const float* W2  = (const float*)d_in[7];
  const float* b2  = (const float*)d_in[8];
  const float* W3  = (const float*)d_in[9];
  const float* b3  = (const float*)d_in[10];
  const int* mid = (const int*)d_in[11];
  const int* aid = (const int*)d_in[12];
  const int* did = (const int*)d_in[13];
  const int* gid = (const int*)d_in[14];
  const int* sid = (const int*)d_in[15];
  const int N = in_sizes[0] / GI;
  const int P = in_sizes[11];
  float* out = (float*)d_out;

  char* ws = (char*)d_ws;
  size_t off = 0;
  auto alloc = [&](size_t bytes) { char* p = ws + off; off = (off + bytes + 255) & ~(size_t)255; return p; };
  unsigned short* AB     = (unsigned short*)alloc((size_t)N * ABW * 2);
  unsigned short* W1ab_t = (unsigned short*)alloc((size_t)ABW * KP * 2);
  unsigned short* W1c_t  = (unsigned short*)alloc((size_t)NP * KP * 2);
  unsigned short* W2_t   = (unsigned short*)alloc((size_t)NP * NP * 2);
  float* projs           = (float*)alloc((size_t)20 * NP * 4);

  const int prep_total = ABW * KP + NP * KP + NP * NP + 20 * NP;
  prep_kernel<<<(prep_total + 255) / 256, 256, 0, stream>>>(W1, W2, b1, de, ge, se,
                                                            W1ab_t, W1c_t, W2_t, projs);
  ab_kernel<<<(N + 63) / 64, 256, 0, stream>>>(g, W1ab_t, AB, N);
  pair_kernel<<<(P + 63) / 64, 256, 0, stream>>>(g, msc, AB, W1c_t, W2_t, projs,
                                                 b2, W3, b3, mid, aid, did, gid, sid,
                                                 out, N, P);
}